// Round 1
// baseline (602.198 us; speedup 1.0000x reference)
//
#include <hip/hip_runtime.h>
#include <math.h>

#define B_ 32
#define S_ 1024
#define H_ 512
#define K_ 1024                 // 2*H
#define M_ (B_ * S_)            // 32768

#define BM 128
#define BN 128
#define BK 32
#define PAD 4                   // keeps LDS rows 16B-aligned for float4 reads

// ---------------------------------------------------------------------------
// Kernel 1: hb[b][h] = sum_k hidden[b][k] * W[k][h] + bias[h]   (W rows 0..H-1)
// ---------------------------------------------------------------------------
__global__ __launch_bounds__(256) void hproj_kernel(
    const float* __restrict__ hidden,   // (B, H)
    const float* __restrict__ W,        // (3H, H) row-major, use rows [0, H)
    const float* __restrict__ bias,     // (H)
    float* __restrict__ hb)             // (B, H) out
{
    const int h = blockIdx.x * blockDim.x + threadIdx.x;  // 0..H-1
    const int b = blockIdx.y;
    if (h >= H_) return;
    const float* hrow = hidden + b * H_;
    float acc = bias[h];
    #pragma unroll 4
    for (int k = 0; k < H_; ++k) {
        acc = fmaf(hrow[k], W[(size_t)k * H_ + h], acc);
    }
    hb[b * H_ + h] = acc;
}

// ---------------------------------------------------------------------------
// Kernel 2: fused GEMM + tanh + v-dot partial reduction.
//   EO (M,K) @ We (K,N=512); per row m: partial[nt][m] = sum over this block's
//   128 columns of tanh(eproj + hb[batch][c]) * v[c]
// ---------------------------------------------------------------------------
__global__ __launch_bounds__(256) void fused_attn_gemm(
    const float* __restrict__ EO,       // (M, K)
    const float* __restrict__ We,       // (K, 512) row-major
    const float* __restrict__ hb,       // (B, H)  (h_proj + bias)
    const float* __restrict__ v,        // (H)
    float* __restrict__ partial)        // (4, M)
{
    __shared__ float As[BK][BM + PAD];  // A stored transposed: As[k][m]
    __shared__ float Bs[BK][BN + PAD];

    const int tid  = threadIdx.x;
    const int mt   = blockIdx.x;        // 0..255
    const int nt   = blockIdx.y;        // 0..3
    const int row0 = mt * BM;
    const int col0 = nt * BN;
    const int batch = row0 / S_;        // BM=128 divides S=1024: one batch/tile

    const int tx = tid & 15;            // 0..15  -> columns
    const int ty = tid >> 4;            // 0..15  -> rows

    float acc[8][8];
    #pragma unroll
    for (int i = 0; i < 8; ++i)
        #pragma unroll
        for (int j = 0; j < 8; ++j) acc[i][j] = 0.0f;

    for (int k0 = 0; k0 < K_; k0 += BK) {
        // ---- stage A tile (BM x BK) transposed into As[k][m] ----
        // float4 unit index f in [0,1024): m = f>>3, kq = f&7 (k = 4*kq)
        #pragma unroll
        for (int q = 0; q < 4; ++q) {
            const int f  = tid + 256 * q;
            const int m  = f >> 3;
            const int kq = f & 7;
            const float4 av = *reinterpret_cast<const float4*>(
                EO + (size_t)(row0 + m) * K_ + k0 + kq * 4);
            As[kq * 4 + 0][m] = av.x;
            As[kq * 4 + 1][m] = av.y;
            As[kq * 4 + 2][m] = av.z;
            As[kq * 4 + 3][m] = av.w;
        }
        // ---- stage B tile (BK x BN): f -> k = f>>5, col = (f&31)*4 ----
        #pragma unroll
        for (int q = 0; q < 4; ++q) {
            const int f  = tid + 256 * q;
            const int k  = f >> 5;
            const int cq = f & 31;
            const float4 bv = *reinterpret_cast<const float4*>(
                We + (size_t)(k0 + k) * H_ + col0 + cq * 4);
            *reinterpret_cast<float4*>(&Bs[k][cq * 4]) = bv;
        }
        __syncthreads();

        // ---- inner product: 8x8 micro-tile, split-4 layout ----
        #pragma unroll
        for (int kk = 0; kk < BK; ++kk) {
            const float4 a0 = *reinterpret_cast<const float4*>(&As[kk][ty * 4]);
            const float4 a1 = *reinterpret_cast<const float4*>(&As[kk][64 + ty * 4]);
            const float4 b0 = *reinterpret_cast<const float4*>(&Bs[kk][tx * 4]);
            const float4 b1 = *reinterpret_cast<const float4*>(&Bs[kk][64 + tx * 4]);
            const float a[8] = {a0.x, a0.y, a0.z, a0.w, a1.x, a1.y, a1.z, a1.w};
            const float b[8] = {b0.x, b0.y, b0.z, b0.w, b1.x, b1.y, b1.z, b1.w};
            #pragma unroll
            for (int i = 0; i < 8; ++i)
                #pragma unroll
                for (int j = 0; j < 8; ++j)
                    acc[i][j] = fmaf(a[i], b[j], acc[i][j]);
        }
        __syncthreads();
    }

    // ---- epilogue: tanh(acc + hb) * v, reduce over columns ----
    const float* hb_row = hb + batch * H_;
    float* red = &As[0][0];             // reuse As LDS: need 128*17 = 2176 floats

    #pragma unroll
    for (int i = 0; i < 8; ++i) {
        const int rloc = (i < 4) ? (ty * 4 + i) : (64 + ty * 4 + i - 4);
        float rs = 0.0f;
        #pragma unroll
        for (int j = 0; j < 8; ++j) {
            const int cloc = (j < 4) ? (tx * 4 + j) : (64 + tx * 4 + j - 4);
            const int c = col0 + cloc;
            const float x = acc[i][j] + hb_row[c];
            rs = fmaf(tanhf(x), v[c], rs);
        }
        red[rloc * 17 + tx] = rs;
    }
    __syncthreads();

    // 128 threads finish the 16-wide reduction per row
    if (tid < BM) {
        const int r = tid;
        float s = 0.0f;
        #pragma unroll
        for (int t = 0; t < 16; ++t) s += red[r * 17 + t];
        partial[(size_t)nt * M_ + row0 + r] = s;
    }
}

// ---------------------------------------------------------------------------
// Kernel 3: per-batch softmax over S=1024 scores (sum of 4 partials)
// ---------------------------------------------------------------------------
__global__ __launch_bounds__(256) void softmax_kernel(
    const float* __restrict__ partial,  // (4, M)
    float* __restrict__ out)            // (B, S)
{
    const int b = blockIdx.x;
    const int tid = threadIdx.x;

    float val[4];
    float lmax = -3.0e38f;
    #pragma unroll
    for (int q = 0; q < 4; ++q) {
        const int s = tid + 256 * q;
        const int idx = b * S_ + s;
        float sum = partial[idx] + partial[M_ + idx] + partial[2 * M_ + idx] +
                    partial[3 * M_ + idx];
        val[q] = sum;
        lmax = fmaxf(lmax, sum);
    }
    // block max
    #pragma unroll
    for (int off = 32; off > 0; off >>= 1)
        lmax = fmaxf(lmax, __shfl_down(lmax, off, 64));
    __shared__ float wmax[4];
    if ((tid & 63) == 0) wmax[tid >> 6] = lmax;
    __syncthreads();
    const float gmax = fmaxf(fmaxf(wmax[0], wmax[1]), fmaxf(wmax[2], wmax[3]));

    float lsum = 0.0f;
    #pragma unroll
    for (int q = 0; q < 4; ++q) {
        val[q] = expf(val[q] - gmax);
        lsum += val[q];
    }
    #pragma unroll
    for (int off = 32; off > 0; off >>= 1)
        lsum += __shfl_down(lsum, off, 64);
    __shared__ float wsum[4];
    if ((tid & 63) == 0) wsum[tid >> 6] = lsum;
    __syncthreads();
    const float inv = 1.0f / (wsum[0] + wsum[1] + wsum[2] + wsum[3]);

    #pragma unroll
    for (int q = 0; q < 4; ++q) {
        const int s = tid + 256 * q;
        out[b * S_ + s] = val[q] * inv;
    }
}

// ---------------------------------------------------------------------------
extern "C" void kernel_launch(void* const* d_in, const int* in_sizes, int n_in,
                              void* d_out, int out_size, void* d_ws, size_t ws_size,
                              hipStream_t stream) {
    const float* hidden = (const float*)d_in[0];   // (B, H)
    const float* EO     = (const float*)d_in[1];   // (B, S, 2H) -> (M, K)
    const float* W      = (const float*)d_in[2];   // (3H, H)
    const float* bias   = (const float*)d_in[3];   // (H)
    const float* v      = (const float*)d_in[4];   // (H)
    float* out          = (float*)d_out;           // (B, S)

    float* hb      = (float*)d_ws;                 // B*H floats      = 64 KB
    float* partial = hb + B_ * H_;                 // 4*M floats      = 512 KB

    const float* We = W + (size_t)H_ * H_;         // rows [H, 3H)

    hproj_kernel<<<dim3(2, B_), 256, 0, stream>>>(hidden, W, bias, hb);
    fused_attn_gemm<<<dim3(M_ / BM, 512 / BN), 256, 0, stream>>>(EO, We, hb, v, partial);
    softmax_kernel<<<B_, 256, 0, stream>>>(partial, out);
}

// Round 2
// 327.600 us; speedup vs baseline: 1.8382x; 1.8382x over previous
//
#include <hip/hip_runtime.h>
#include <math.h>

#define B_ 32
#define S_ 1024
#define H_ 512
#define K_ 1024                 // 2*H
#define M_ (B_ * S_)            // 32768

typedef __attribute__((ext_vector_type(8))) short bf16x8;
typedef __attribute__((ext_vector_type(4))) float f32x4;

#define AST 40                  // LDS row stride (elements): 32 + 8 pad -> 80 B, 16B-aligned, <=2-way banks

// RNE split: f = hi + lo with hi,lo bf16; dropped cross-term ~2^-18 relative
__device__ __forceinline__ void split_bf16(float f, unsigned short& hi, unsigned short& lo) {
    unsigned u = __float_as_uint(f);
    unsigned rh = (u + 0x7fffu + ((u >> 16) & 1u)) >> 16;
    hi = (unsigned short)rh;
    float fh = __uint_as_float(rh << 16);
    float r = f - fh;                      // exact (Veltkamp-style split)
    unsigned ur = __float_as_uint(r);
    unsigned rl = (ur + 0x7fffu + ((ur >> 16) & 1u)) >> 16;
    lo = (unsigned short)rl;
}

// ---------------------------------------------------------------------------
// Kernel 1: hb[b][h] = sum_k hidden[b][k]*W[k][h] + bias[h]  — k-split, 256 blocks
// ---------------------------------------------------------------------------
__global__ __launch_bounds__(256) void hproj_kernel(
    const float* __restrict__ hidden, const float* __restrict__ W,
    const float* __restrict__ bias, float* __restrict__ hb)
{
    const int tid = threadIdx.x;
    const int h0  = blockIdx.x * 64;
    const int b   = blockIdx.y;
    const int h   = h0 + (tid & 63);
    const int ks  = tid >> 6;              // 4 k-slices of 128
    const float* hrow = hidden + b * H_;
    float acc = 0.f;
    #pragma unroll 8
    for (int k = ks * 128; k < ks * 128 + 128; ++k)
        acc = fmaf(hrow[k], W[(size_t)k * H_ + h], acc);
    __shared__ float red[4][64];
    red[ks][tid & 63] = acc;
    __syncthreads();
    if (tid < 64)
        hb[b * H_ + h0 + tid] = red[0][tid] + red[1][tid] + red[2][tid] + red[3][tid]
                              + bias[h0 + tid];
}

// ---------------------------------------------------------------------------
// Kernel 1b: transpose + bf16-split We (K x 512) -> Wth/Wtl (512 x K)
// ---------------------------------------------------------------------------
__global__ __launch_bounds__(256) void conv_we_kernel(
    const float* __restrict__ We, unsigned short* __restrict__ Wh,
    unsigned short* __restrict__ Wl)
{
    __shared__ float t[32][33];
    const int tx = threadIdx.x & 31, ty = threadIdx.x >> 5;   // ty 0..7
    const int k0 = blockIdx.x * 32, n0 = blockIdx.y * 32;
    #pragma unroll
    for (int j = 0; j < 4; ++j) {
        const int k = ty + 8 * j;
        t[k][tx] = We[(size_t)(k0 + k) * H_ + n0 + tx];
    }
    __syncthreads();
    #pragma unroll
    for (int j = 0; j < 4; ++j) {
        const int n = ty + 8 * j;
        unsigned short hi, lo;
        split_bf16(t[tx][n], hi, lo);
        Wh[(size_t)(n0 + n) * K_ + k0 + tx] = hi;
        Wl[(size_t)(n0 + n) * K_ + k0 + tx] = lo;
    }
}

// ---------------------------------------------------------------------------
// Kernel 2: MFMA GEMM (split-bf16 x3) + fused tanh/v-dot row reduction.
//   Block tile 128x128, BK=32, 4 waves of 64x64, 16x16x32 bf16 MFMA.
//   A layout: lane holds A[m=lane&15][k=quad*8+j]; C: col=lane&15,row=quad*4+r.
// ---------------------------------------------------------------------------
__global__ __launch_bounds__(256, 3) void fused_attn_gemm_mfma(
    const float* __restrict__ EO,             // (M, K) fp32
    const unsigned short* __restrict__ Bth,   // (512, K) bf16 hi (pre-transposed)
    const unsigned short* __restrict__ Btl,   // (512, K) bf16 lo
    const float* __restrict__ hb,             // (B, H)
    const float* __restrict__ v,              // (H)
    float* __restrict__ partial)              // (4, M)
{
    __shared__ unsigned short Ah[128 * AST];
    __shared__ unsigned short Al[128 * AST];
    __shared__ unsigned short Bh[128 * AST];
    __shared__ unsigned short Bl[128 * AST];

    const int tid  = threadIdx.x;
    const int nt   = blockIdx.x;              // 0..3   (fastest: A L3 reuse)
    const int mt   = blockIdx.y;              // 0..255
    const int row0 = mt * 128;
    const int col0 = nt * 128;
    const int batch = row0 >> 10;             // 128 | 1024

    const int lane   = tid & 63;
    const int wave   = tid >> 6;
    const int wm     = wave >> 1, wn = wave & 1;
    const int lanelo = lane & 15, quad = lane >> 4;

    f32x4 acc[4][4];
    #pragma unroll
    for (int i = 0; i < 4; ++i)
        #pragma unroll
        for (int j = 0; j < 4; ++j)
            acc[i][j] = (f32x4){0.f, 0.f, 0.f, 0.f};

    for (int k0 = 0; k0 < K_; k0 += 32) {
        // ---- stage A: load fp32, split to bf16 hi/lo ----
        #pragma unroll
        for (int q = 0; q < 4; ++q) {
            const int f = tid + 256 * q;
            const int m = f >> 3, c = f & 7;
            const float4 av = *reinterpret_cast<const float4*>(
                EO + (size_t)(row0 + m) * K_ + k0 + c * 4);
            union { unsigned short us[4]; uint2 u2; } ph, pl;
            split_bf16(av.x, ph.us[0], pl.us[0]);
            split_bf16(av.y, ph.us[1], pl.us[1]);
            split_bf16(av.z, ph.us[2], pl.us[2]);
            split_bf16(av.w, ph.us[3], pl.us[3]);
            *reinterpret_cast<uint2*>(&Ah[m * AST + c * 4]) = ph.u2;
            *reinterpret_cast<uint2*>(&Al[m * AST + c * 4]) = pl.u2;
        }
        // ---- stage B: straight 16B copies of pre-split tiles ----
        #pragma unroll
        for (int q = 0; q < 2; ++q) {
            const int s = tid + 256 * q;
            const int n = s >> 2, qq = s & 3;
            const size_t g = (size_t)(col0 + n) * K_ + k0 + qq * 8;
            *reinterpret_cast<uint4*>(&Bh[n * AST + qq * 8]) =
                *reinterpret_cast<const uint4*>(Bth + g);
            *reinterpret_cast<uint4*>(&Bl[n * AST + qq * 8]) =
                *reinterpret_cast<const uint4*>(Btl + g);
        }
        __syncthreads();

        // ---- fragments ----
        bf16x8 a_h[4], a_l[4], b_h[4], b_l[4];
        #pragma unroll
        for (int fi = 0; fi < 4; ++fi) {
            const int m = wm * 64 + fi * 16 + lanelo;
            a_h[fi] = *reinterpret_cast<const bf16x8*>(&Ah[m * AST + quad * 8]);
            a_l[fi] = *reinterpret_cast<const bf16x8*>(&Al[m * AST + quad * 8]);
            const int n = wn * 64 + fi * 16 + lanelo;
            b_h[fi] = *reinterpret_cast<const bf16x8*>(&Bh[n * AST + quad * 8]);
            b_l[fi] = *reinterpret_cast<const bf16x8*>(&Bl[n * AST + quad * 8]);
        }
        #pragma unroll
        for (int fi = 0; fi < 4; ++fi)
            #pragma unroll
            for (int fj = 0; fj < 4; ++fj) {
                acc[fi][fj] = __builtin_amdgcn_mfma_f32_16x16x32_bf16(
                    a_h[fi], b_h[fj], acc[fi][fj], 0, 0, 0);
                acc[fi][fj] = __builtin_amdgcn_mfma_f32_16x16x32_bf16(
                    a_h[fi], b_l[fj], acc[fi][fj], 0, 0, 0);
                acc[fi][fj] = __builtin_amdgcn_mfma_f32_16x16x32_bf16(
                    a_l[fi], b_h[fj], acc[fi][fj], 0, 0, 0);
            }
        __syncthreads();
    }

    // ---- epilogue: tanh(acc + hb)*v, reduce over this block's 128 cols ----
    const float* hb_row = hb + batch * H_;
    float hbv[4], vv[4];
    #pragma unroll
    for (int fj = 0; fj < 4; ++fj) {
        const int c = col0 + wn * 64 + fj * 16 + lanelo;
        hbv[fj] = hb_row[c];
        vv[fj]  = v[c];
    }
    float* red = reinterpret_cast<float*>(Ah);   // 256 floats, reuse LDS
    #pragma unroll
    for (int fi = 0; fi < 4; ++fi)
        #pragma unroll
        for (int r = 0; r < 4; ++r) {
            float rs = 0.f;
            #pragma unroll
            for (int fj = 0; fj < 4; ++fj)
                rs = fmaf(tanhf(acc[fi][fj][r] + hbv[fj]), vv[fj], rs);
            rs += __shfl_xor(rs, 1, 64);
            rs += __shfl_xor(rs, 2, 64);
            rs += __shfl_xor(rs, 4, 64);
            rs += __shfl_xor(rs, 8, 64);
            if (lanelo == 0) {
                const int row = wm * 64 + fi * 16 + quad * 4 + r;
                red[row * 2 + wn] = rs;
            }
        }
    __syncthreads();
    if (tid < 128)
        partial[(size_t)nt * M_ + row0 + tid] = red[tid * 2] + red[tid * 2 + 1];
}

// ---------------------------------------------------------------------------
// Fallback fp32 GEMM (used only if ws_size too small for the bf16-split path)
// ---------------------------------------------------------------------------
#define BM 128
#define BN 128
#define BK 32
#define PAD 4
__global__ __launch_bounds__(256) void fused_attn_gemm_fp32(
    const float* __restrict__ EO, const float* __restrict__ We,
    const float* __restrict__ hb, const float* __restrict__ v,
    float* __restrict__ partial)
{
    __shared__ float As[BK][BM + PAD];
    __shared__ float Bs[BK][BN + PAD];
    const int tid = threadIdx.x;
    const int mt = blockIdx.x, nt = blockIdx.y;
    const int row0 = mt * BM, col0 = nt * BN;
    const int batch = row0 / S_;
    const int tx = tid & 15, ty = tid >> 4;
    float acc[8][8];
    #pragma unroll
    for (int i = 0; i < 8; ++i)
        #pragma unroll
        for (int j = 0; j < 8; ++j) acc[i][j] = 0.0f;
    for (int k0 = 0; k0 < K_; k0 += BK) {
        #pragma unroll
        for (int q = 0; q < 4; ++q) {
            const int f = tid + 256 * q;
            const int m = f >> 3, kq = f & 7;
            const float4 av = *reinterpret_cast<const float4*>(
                EO + (size_t)(row0 + m) * K_ + k0 + kq * 4);
            As[kq * 4 + 0][m] = av.x; As[kq * 4 + 1][m] = av.y;
            As[kq * 4 + 2][m] = av.z; As[kq * 4 + 3][m] = av.w;
        }
        #pragma unroll
        for (int q = 0; q < 4; ++q) {
            const int f = tid + 256 * q;
            const int k = f >> 5, cq = f & 31;
            *reinterpret_cast<float4*>(&Bs[k][cq * 4]) =
                *reinterpret_cast<const float4*>(We + (size_t)(k0 + k) * H_ + col0 + cq * 4);
        }
        __syncthreads();
        #pragma unroll
        for (int kk = 0; kk < BK; ++kk) {
            const float4 a0 = *reinterpret_cast<const float4*>(&As[kk][ty * 4]);
            const float4 a1 = *reinterpret_cast<const float4*>(&As[kk][64 + ty * 4]);
            const float4 b0 = *reinterpret_cast<const float4*>(&Bs[kk][tx * 4]);
            const float4 b1 = *reinterpret_cast<const float4*>(&Bs[kk][64 + tx * 4]);
            const float a[8] = {a0.x, a0.y, a0.z, a0.w, a1.x, a1.y, a1.z, a1.w};
            const float b[8] = {b0.x, b0.y, b0.z, b0.w, b1.x, b1.y, b1.z, b1.w};
            #pragma unroll
            for (int i = 0; i < 8; ++i)
                #pragma unroll
                for (int j = 0; j < 8; ++j)
                    acc[i][j] = fmaf(a[i], b[j], acc[i][j]);
        }
        __syncthreads();
    }
    const float* hb_row = hb + batch * H_;
    float* red = &As[0][0];
    #pragma unroll
    for (int i = 0; i < 8; ++i) {
        const int rloc = (i < 4) ? (ty * 4 + i) : (64 + ty * 4 + i - 4);
        float rs = 0.0f;
        #pragma unroll
        for (int j = 0; j < 8; ++j) {
            const int cloc = (j < 4) ? (tx * 4 + j) : (64 + tx * 4 + j - 4);
            const int c = col0 + cloc;
            rs = fmaf(tanhf(acc[i][j] + hb_row[c]), v[c], rs);
        }
        red[rloc * 17 + tx] = rs;
    }
    __syncthreads();
    if (tid < BM) {
        float s = 0.0f;
        #pragma unroll
        for (int t = 0; t < 16; ++t) s += red[tid * 17 + t];
        partial[(size_t)nt * M_ + row0 + tid] = s;
    }
}

// ---------------------------------------------------------------------------
// Kernel 3: per-batch softmax over S=1024 (sum of 4 partials)
// ---------------------------------------------------------------------------
__global__ __launch_bounds__(256) void softmax_kernel(
    const float* __restrict__ partial, float* __restrict__ out)
{
    const int b = blockIdx.x;
    const int tid = threadIdx.x;
    float val[4];
    float lmax = -3.0e38f;
    #pragma unroll
    for (int q = 0; q < 4; ++q) {
        const int idx = b * S_ + tid + 256 * q;
        float sum = partial[idx] + partial[M_ + idx] + partial[2 * M_ + idx] +
                    partial[3 * M_ + idx];
        val[q] = sum;
        lmax = fmaxf(lmax, sum);
    }
    #pragma unroll
    for (int off = 32; off > 0; off >>= 1)
        lmax = fmaxf(lmax, __shfl_down(lmax, off, 64));
    __shared__ float wmax[4];
    if ((tid & 63) == 0) wmax[tid >> 6] = lmax;
    __syncthreads();
    const float gmax = fmaxf(fmaxf(wmax[0], wmax[1]), fmaxf(wmax[2], wmax[3]));
    float lsum = 0.0f;
    #pragma unroll
    for (int q = 0; q < 4; ++q) {
        val[q] = expf(val[q] - gmax);
        lsum += val[q];
    }
    #pragma unroll
    for (int off = 32; off > 0; off >>= 1)
        lsum += __shfl_down(lsum, off, 64);
    __shared__ float wsum[4];
    if ((tid & 63) == 0) wsum[tid >> 6] = lsum;
    __syncthreads();
    const float inv = 1.0f / (wsum[0] + wsum[1] + wsum[2] + wsum[3]);
    #pragma unroll
    for (int q = 0; q < 4; ++q)
        out[b * S_ + tid + 256 * q] = val[q] * inv;
}

// ---------------------------------------------------------------------------
extern "C" void kernel_launch(void* const* d_in, const int* in_sizes, int n_in,
                              void* d_out, int out_size, void* d_ws, size_t ws_size,
                              hipStream_t stream) {
    const float* hidden = (const float*)d_in[0];
    const float* EO     = (const float*)d_in[1];
    const float* W      = (const float*)d_in[2];
    const float* bias   = (const float*)d_in[3];
    const float* v      = (const float*)d_in[4];
    float* out          = (float*)d_out;

    float* hb      = (float*)d_ws;                       // 16384 floats
    float* partial = hb + B_ * H_;                       // 131072 floats
    unsigned short* Wth = (unsigned short*)(partial + 4 * M_);
    unsigned short* Wtl = Wth + (size_t)H_ * K_;
    const size_t needed = (size_t)(B_ * H_ + 4 * M_) * sizeof(float)
                        + (size_t)H_ * K_ * 2 * sizeof(unsigned short);

    const float* We = W + (size_t)H_ * H_;               // rows [H, 3H)

    hproj_kernel<<<dim3(8, B_), 256, 0, stream>>>(hidden, W, bias, hb);
    if (ws_size >= needed) {
        conv_we_kernel<<<dim3(K_ / 32, H_ / 32), 256, 0, stream>>>(We, Wth, Wtl);
        fused_attn_gemm_mfma<<<dim3(4, M_ / 128), 256, 0, stream>>>(EO, Wth, Wtl, hb, v, partial);
    } else {
        fused_attn_gemm_fp32<<<dim3(M_ / BM, 4), 256, 0, stream>>>(EO, We, hb, v, partial);
    }
    softmax_kernel<<<B_, 256, 0, stream>>>(partial, out);
}